// Round 14
// baseline (2777.148 us; speedup 1.0000x reference)
//
#include <hip/hip_runtime.h>

typedef unsigned short u16;
typedef unsigned int u32;
typedef __attribute__((ext_vector_type(8))) u16 u16x8;
typedef __attribute__((ext_vector_type(8))) __bf16 bf16x8;
typedef __attribute__((ext_vector_type(4))) float f32x4;

#define DEV static __device__ __forceinline__

DEV float b2f(u16 u){ unsigned int i = ((unsigned int)u)<<16; float f; __builtin_memcpy(&f,&i,4); return f; }
DEV u16 f2b(float f){ unsigned int x; __builtin_memcpy(&x,&f,4); x = x + 0x7fffu + ((x>>16)&1u); return (u16)(x>>16); }

// async global->LDS 16B: HW writes lane i's data at ldsbase + i*16 (wave-uniform base)
DEV void gll16(const u16* g, u16* l){
    __builtin_amdgcn_global_load_lds(
        (const __attribute__((address_space(1))) u32*)(const void*)g,
        (__attribute__((address_space(3))) u32*)(void*)l, 16, 0, 0);
}

// load 8 contiguous elements as bf16x8-bits; F32 converts fp32->bf16 (RTN)
template<bool F32>
DEV u16x8 ld8(const void* base, long off){
    if constexpr (F32){
        const float* p = (const float*)base + off;
        float4 a = *(const float4*)p;
        float4 b = *(const float4*)(p+4);
        u16x8 r;
        r[0]=f2b(a.x); r[1]=f2b(a.y); r[2]=f2b(a.z); r[3]=f2b(a.w);
        r[4]=f2b(b.x); r[5]=f2b(b.y); r[6]=f2b(b.z); r[7]=f2b(b.w);
        return r;
    } else {
        return *(const u16x8*)((const u16*)base + off);
    }
}
template<bool F32>
DEV const void* vadd(const void* p, long elems){
    if constexpr (F32) return (const void*)((const float*)p + elems);
    else               return (const void*)((const u16*)p + elems);
}

// B=32 D=768 H=8 L=6 E=8 NL=256 P=16 IMG=224 NT=10 G=14 NP=196 HD=96 TOPK=2
#define LAT_ELEMS 6291456   // 32*256*768
#define NVIS 49
#define NMASK 147
#define T_TOK 8192          // 32*256
#define MOE_CAP 17408       // 2*8192 + 8*128 pad
#define MOE_HALF 8704
#define KOFF 6291456L       // Kb offset within common (elems)
#define VOFF 12582912L      // Vt offset within common (elems)

// ---------------- fp32 -> bf16 weight conversion (RTN, identical to staging) ----------------
__global__ __launch_bounds__(256) void wconv(const float* __restrict__ src, u16* __restrict__ dst, long n)
{
    long i = ((long)blockIdx.x*256 + threadIdx.x)*8;
    if (i >= n) return;
    *(u16x8*)(dst + i) = ld8<true>(src, i);
}

// ---------------- argsort (stable, ascending), fp32 noise, fp32 index outputs ----------------
__global__ __launch_bounds__(256) void argsort_k(const float* __restrict__ noise,
                                                 int* __restrict__ order,
                                                 float* __restrict__ dout,
                                                 u16* __restrict__ zbuf)
{
    __shared__ float vals[196];
    __shared__ int ord[196];
    int b = blockIdx.x, tid = threadIdx.x;
    if (b == 0 && tid < 128) zbuf[tid] = 0;     // zero page for gll redirects
    if (tid < 196) vals[tid] = noise[b*196 + tid];
    __syncthreads();
    if (tid < 196){
        float vi = vals[tid]; int rank = 0;
        for (int j=0;j<196;j++){ float vj = vals[j]; rank += (vj < vi) || (vj == vi && j < tid); }
        ord[rank] = tid;
    }
    __syncthreads();
    if (tid < 196){
        int v = ord[tid];
        order[b*196 + tid] = v;
        if (tid < NVIS) dout[LAT_ELEMS + b*NVIS + tid] = (float)v;
        else            dout[LAT_ELEMS + 32*NVIS + b*NMASK + (tid - NVIS)] = (float)v;
    }
}

// ---------------- gather visible patch pixels (fp32 images) into bf16 Ap (1664x768) ----------------
__global__ __launch_bounds__(256) void patch_gather(const float* __restrict__ images,
                                                    const int* __restrict__ order,
                                                    u16* __restrict__ Ap)
{
    int i = blockIdx.x*256 + threadIdx.x;   // over 1664*48
    int t = i/48, kc = i - t*48;
    if (t >= 1664) return;
    if (t >= 1568){
        u16x8 z{};
        *(u16x8*)(Ap + (long)t*768 + kc*16)     = z;
        *(u16x8*)(Ap + (long)t*768 + kc*16 + 8) = z;
        return;
    }
    int b = t/49, vi = t - b*49;
    int p = order[b*196 + vi];
    int c = kc >> 4, py = kc & 15;
    int gy = p/14, gx = p - gy*14;
    const float* src = images + (((long)(b*3 + c)*224 + gy*16 + py)*224 + gx*16);
    u16x8 o0 = ld8<true>(src, 0);
    u16x8 o1 = ld8<true>(src, 8);
    *(u16x8*)(Ap + (long)t*768 + kc*16)     = o0;
    *(u16x8*)(Ap + (long)t*768 + kc*16 + 8) = o1;
}

// ---------------- add pos_emb + type_emb (fp32) to bf16 vis ----------------
__global__ __launch_bounds__(256) void add_pos_type(u16* __restrict__ vis,
                                                    const int* __restrict__ order,
                                                    const int* __restrict__ type_ids,
                                                    const float* __restrict__ pos,
                                                    const float* __restrict__ temb)
{
    int i = blockIdx.x*256 + threadIdx.x;   // 1568*96
    int t = i/96, dc = (i - t*96)*8;
    if (t >= 1568) return;
    int b = t/49, vi = t - b*49;
    int p = order[b*196 + vi], tb = type_ids[b];
    u16x8 a = *(u16x8*)(vis + (long)t*768 + dc);
    const float* pp = pos  + (long)p*768 + dc;
    const float* tt = temb + (long)tb*768 + dc;
    float4 p0 = *(const float4*)pp, p1 = *(const float4*)(pp+4);
    float4 t0 = *(const float4*)tt, t1 = *(const float4*)(tt+4);
    u16x8 o;
    o[0]=f2b(b2f(a[0])+p0.x+t0.x); o[1]=f2b(b2f(a[1])+p0.y+t0.y);
    o[2]=f2b(b2f(a[2])+p0.z+t0.z); o[3]=f2b(b2f(a[3])+p0.w+t0.w);
    o[4]=f2b(b2f(a[4])+p1.x+t1.x); o[5]=f2b(b2f(a[5])+p1.y+t1.y);
    o[6]=f2b(b2f(a[6])+p1.z+t1.z); o[7]=f2b(b2f(a[7])+p1.w+t1.w);
    *(u16x8*)(vis + (long)t*768 + dc) = o;
}

// ---------------- generic NT GEMM ----------------
// C[M,N](bf16) = epi(scale*A[M,K]@B[N,K]^T + bias)
// MT: row-tile (64/128). GRP=0 plain (z-batched); GRP=1 MoE-FFN1 (A rows via tos[], MT=128);
// GRP=2 MoE-FFN2 (C at row_base+row); GRP=3 fused QKV epilogue (MT=128, V-third ushort4-fused).
// SWZ: bijective XCD remap. GLL: global_load_lds w16 staging.
// PIPE (requires GLL,MT=128): T4 counted-vmcnt double-buffer — stage tile t+1 into buf^1,
//   s_waitcnt vmcnt(8) (only tile t's per-wave loads), raw s_barrier (no vmcnt(0) drain),
//   MFMA, raw s_barrier. LDS 64KB -> 2 blocks/CU; the in-flight loads pay for the occupancy.
// NOTE: min-waves pinned at 4 — (256,5) caps VGPR below acc needs -> scratch spill (r9: 364MB WRITE).
template<int BK, int MT, bool BIAS, bool GELU, int GRP, bool AF32, bool BF32, bool SWZ, bool GLL, bool PIPE>
__global__ __launch_bounds__(256,4) void gemm_nt(
    const void* __restrict__ A, const void* __restrict__ B, const float* __restrict__ bias,
    u16* __restrict__ C,
    int M, int N, int K, int lda, int ldb, int ldc,
    float scale, int ZLO, int NB,
    long sAh, long sAl, long sBh, long sBl, long sCh, long sCl,
    const int* __restrict__ aoff, const int* __restrict__ tos, const u16* __restrict__ zbuf,
    int row_base, long sBE, long sBiasE)
{
    int bx = blockIdx.x, by = blockIdx.y;
    if (SWZ){
        int nx = gridDim.x, ny = gridDim.y;
        int nwg = nx*ny;
        int flat = by*nx + bx;
        int q = nwg >> 3, r = nwg & 7;
        int xcd = flat & 7, idx = flat >> 3;
        int wg = (xcd < r ? xcd*(q+1) : r*(q+1) + (xcd - r)*q) + idx;
        bx = wg % nx; by = wg / nx;
    }
    int z = blockIdx.z; int zh = z / ZLO, zl = z - zh*ZLO;
    const void* Ab = vadd<AF32>(A, zh*sAh + zl*sAl);
    const void* Bb = vadd<BF32>(B, zh*sBh + zl*sBl);
    u16* Cb = C + zh*sCh + zl*sCl;
    const float* biasb = bias;
    int row0 = by*MT, col0 = bx*128;
    int lim = 0;
    if (GRP == 1 || GRP == 2){
        lim = aoff[8];
        int g0 = row_base + row0;
        if (g0 >= lim) return;
        int e = 0;
        #pragma unroll
        for (int i=1;i<8;i++) if (g0 >= aoff[i]) e = i;
        Bb = vadd<BF32>(B, (long)e*sBE);
        if (BIAS) biasb = bias + (long)e*sBiasE;
    }
    constexpr int SP = GLL ? BK : BK + 8;
    constexpr int MR = MT/32;           // acc row-frags per wave
    constexpr int NBUF = PIPE ? 2 : 1;
    __shared__ __align__(16) u16 As[NBUF*MT*SP];
    __shared__ __align__(16) u16 Bs[NBUF*128*SP];
    int tid = threadIdx.x;
    int lane = tid & 63, wv = tid >> 6;
    int wr = (wv>>1)*(MT/2), wc = (wv&1)*64;
    f32x4 acc[MR][4];
    #pragma unroll
    for (int m=0;m<MR;m++){
        #pragma unroll
        for (int n=0;n<4;n++) acc[m][n] = f32x4{0.f,0.f,0.f,0.f};
    }
    constexpr int RPC = BK/8;           // 16B chunks per row
    constexpr int RPI = 64/RPC;         // rows per wave-issue (GLL)
    constexpr int NJA = MT*RPC/256;     // A issues per wave (GLL)
    constexpr int NJB = 128*RPC/256;    // B issues per wave (GLL)
    constexpr int NISSUE = NJA + NJB;   // gll per wave per stage
    constexpr int PER = 128*RPC/256;    // chunks per thread per matrix (old path, MT=128)
    int tA[4];
    if (GRP == 1){
        #pragma unroll
        for (int j=0;j<NJA;j++){
            int r = wv*(MT/4) + j*RPI + (lane/RPC);
            tA[j] = tos[row_base + row0 + r];
        }
    }
    auto stage = [&](int k0, int boff){
        int ch = lane % RPC;
        #pragma unroll
        for (int j=0;j<NJA;j++){
            int r  = wv*(MT/4) + j*RPI + (lane/RPC);
            const u16* sa;
            if (GRP == 1){
                int t = tA[j];
                sa = (t >= 0) ? (const u16*)Ab + (long)t*lda + k0 + ch*8 : zbuf + ch*8;
            } else {
                sa = (const u16*)Ab + (long)(row0+r)*lda + k0 + ch*8;
            }
            gll16(sa, As + boff*MT*SP + (wv*(MT/4) + j*RPI)*BK);
        }
        #pragma unroll
        for (int j=0;j<NJB;j++){
            int r = wv*32 + j*RPI + (lane/RPC);
            const u16* sb = (col0 + r < NB) ? (const u16*)Bb + (long)(col0+r)*ldb + k0 + ch*8
                                            : zbuf + ch*8;
            gll16(sb, Bs + boff*128*SP + (wv*32 + j*RPI)*BK);
        }
    };
    auto mfma_tile = [&](int boff){
        #pragma unroll
        for (int kk=0; kk<BK/32; kk++){
            bf16x8 af[MR], bg[4];
            #pragma unroll
            for (int m=0;m<MR;m++)
                af[m] = *(const bf16x8*)(As + boff*MT*SP + (wr + m*16 + (lane&15))*SP + kk*32 + (lane>>4)*8);
            #pragma unroll
            for (int n=0;n<4;n++)
                bg[n] = *(const bf16x8*)(Bs + boff*128*SP + (wc + n*16 + (lane&15))*SP + kk*32 + (lane>>4)*8);
            #pragma unroll
            for (int m=0;m<MR;m++){
                #pragma unroll
                for (int n=0;n<4;n++)
                    acc[m][n] = __builtin_amdgcn_mfma_f32_16x16x32_bf16(af[m], bg[n], acc[m][n], 0,0,0);
            }
        }
    };
    if constexpr (PIPE && GLL){
        int NT = K/BK;
        stage(0, 0);
        for (int t=0; t<NT; ++t){
            int cur = t & 1;
            if (t+1 < NT){
                stage((t+1)*BK, cur^1);
                asm volatile("s_waitcnt vmcnt(%0)" :: "n"(NISSUE) : "memory");
            } else {
                asm volatile("s_waitcnt vmcnt(0)" ::: "memory");
            }
            __builtin_amdgcn_sched_barrier(0);
            __builtin_amdgcn_s_barrier();
            __builtin_amdgcn_sched_barrier(0);
            mfma_tile(cur);
            __builtin_amdgcn_sched_barrier(0);
            __builtin_amdgcn_s_barrier();
        }
    } else {
        for (int k0=0; k0<K; k0+=BK){
            if constexpr (GLL){
                stage(k0, 0);
            } else if constexpr (MT == 128){
                #pragma unroll
                for (int j=0;j<PER;j++){
                    int c = j*256 + tid;
                    int r = c / RPC, cc = (c - r*RPC)*8;
                    u16x8 va{}, vb{};
                    if (GRP == 1){
                        int t = tA[j];
                        if (t >= 0) va = ld8<AF32>(Ab, (long)t*lda + k0 + cc);
                    } else {
                        va = ld8<AF32>(Ab, (long)(row0+r)*lda + k0 + cc);
                    }
                    if (col0 + r < NB) vb = ld8<BF32>(Bb, (long)(col0+r)*ldb + k0 + cc);
                    *(u16x8*)(As + r*SP + cc) = va;
                    *(u16x8*)(Bs + r*SP + cc) = vb;
                }
            }
            __syncthreads();
            mfma_tile(0);
            __syncthreads();
        }
    }
    if (GRP == 3){
        // fused QKV epilogue: M=8192 exact, all rows valid; V-third gets ushort4-fused stores
        #pragma unroll
        for (int m=0;m<MR;m++){
            int rbase = row0 + wr + m*16 + ((lane>>4)<<2);
            #pragma unroll
            for (int n=0;n<4;n++){
                int col = col0 + wc + n*16 + (lane&15);
                float bv = biasb[col];
                if (col < 1536){
                    u16* base = (col < 768) ? Cb : Cb + sBE - 768;
                    #pragma unroll
                    for (int j=0;j<4;j++)
                        base[(long)(rbase+j)*768 + col] = f2b(acc[m][n][j]*scale + bv);
                } else {
                    int c96 = col - 1536;
                    int h = c96/96, d = c96 - h*96;
                    ushort4 o4;
                    o4.x = f2b(acc[m][n][0]*scale + bv);
                    o4.y = f2b(acc[m][n][1]*scale + bv);
                    o4.z = f2b(acc[m][n][2]*scale + bv);
                    o4.w = f2b(acc[m][n][3]*scale + bv);
                    *(ushort4*)(Cb + sBiasE + ((long)((rbase>>8)*8 + h)*96 + d)*256 + (rbase & 255)) = o4;
                }
            }
        }
        return;
    }
    #pragma unroll
    for (int m=0;m<MR;m++){
        int rbase = row0 + wr + m*16 + ((lane>>4)<<2);
        #pragma unroll
        for (int n=0;n<4;n++){
            int col = col0 + wc + n*16 + (lane&15);
            if (col < N){
                float bv = BIAS ? biasb[col] : 0.f;
                #pragma unroll
                for (int j=0;j<4;j++){
                    int row = rbase + j;
                    bool ok = (row < M);
                    if (GRP == 1 || GRP == 2) ok = ok && (row_base + row) < lim;
                    if (ok){
                        float v = acc[m][n][j]*scale + bv;
                        if (GELU) v = 0.5f*v*(1.f + erff(v*0.70710678118f));
                        u16 ov = f2b(v);
                        if (GRP == 2){
                            Cb[(long)(row_base + row)*ldc + col] = ov;
                        } else {
                            Cb[(long)row*ldc + col] = ov;
                        }
                    }
                }
            }
        }
    }
}

// ---------------- fused scores+softmax: S[z] = softmax(Q K^T / sqrt(96)), bf16 out ----------------
// grid (4, 256): blockIdx.x = 64-row block, blockIdx.y = z = b*8+h. 4 waves; wave owns 16 rows x 256 cols.
__global__ __launch_bounds__(256,4) void scores_sm(const u16* __restrict__ Q,
                                                   const u16* __restrict__ K,
                                                   u16* __restrict__ S)
{
    __shared__ __align__(16) u16 As[64*32];
    __shared__ __align__(16) u16 Bs[256*32];
    int z = blockIdx.y;
    int b = z >> 3, h = z & 7;
    const u16* Ab = Q + (long)b*196608 + h*96 + (long)blockIdx.x*64*768;
    const u16* Bb = K + (long)b*196608 + h*96;
    int tid = threadIdx.x, lane = tid & 63, wv = tid >> 6;
    f32x4 acc[16];
    #pragma unroll
    for (int n=0;n<16;n++) acc[n] = f32x4{0.f,0.f,0.f,0.f};
    int ch = lane & 3, rr = lane >> 2;
    for (int k0=0;k0<96;k0+=32){
        gll16(Ab + (long)(wv*16 + rr)*768 + k0 + ch*8, As + (wv*16)*32);
        #pragma unroll
        for (int jj=0;jj<4;jj++)
            gll16(Bb + (long)(wv*64 + jj*16 + rr)*768 + k0 + ch*8, Bs + (wv*64 + jj*16)*32);
        __syncthreads();
        bf16x8 af = *(const bf16x8*)(As + (wv*16 + (lane&15))*32 + (lane>>4)*8);
        #pragma unroll
        for (int n=0;n<16;n++){
            bf16x8 bg = *(const bf16x8*)(Bs + (n*16 + (lane&15))*32 + (lane>>4)*8);
            acc[n] = __builtin_amdgcn_mfma_f32_16x16x32_bf16(af, bg, acc[n], 0,0,0);
        }
        __syncthreads();
    }
    const float SCL = 0.10206207f;    // 1/sqrt(96)
    u16* Sz = S + (long)z*65536 + (long)blockIdx.x*64*256;
    #pragma unroll
    for (int j=0;j<4;j++){
        float mx = -1e30f;
        #pragma unroll
        for (int n=0;n<16;n++) mx = fmaxf(mx, acc[n][j]);
        #pragma unroll
        for (int off=8; off>=1; off>>=1) mx = fmaxf(mx, __shfl_xor(mx, off, 64));
        float ev[16]; float sum = 0.f;
        #pragma unroll
        for (int n=0;n<16;n++){ ev[n] = __expf((acc[n][j]-mx)*SCL); sum += ev[n]; }
        #pragma unroll
        for (int off=8; off>=1; off>>=1) sum += __shfl_xor(sum, off, 64);
        float inv = 1.f/sum;
        int row = wv*16 + ((lane>>4)<<2) + j;
        #pragma unroll
        for (int n=0;n<16;n++) Sz[(long)row*256 + n*16 + (lane&15)] = f2b(ev[n]*inv);
    }
}

// ---------------- cross-attention (kv len 49), bf16 in/out ----------------
__global__ __launch_bounds__(256) void ca_attn(const u16* __restrict__ Qc,   // 256x768
                                               const u16* __restrict__ KV,   // 1664x1536 (K|V)
                                               u16* __restrict__ attn_out)   // 8192x768
{
    __shared__ float Sm[256*49];
    __shared__ u16 KVs[49*96];
    int b = blockIdx.x, h = blockIdx.y, q = threadIdx.x;
    for (int i=q; i<49*96; i+=256){ int k=i/96, d=i-k*96; KVs[i] = KV[(long)(b*49+k)*1536 + h*96 + d]; }
    __syncthreads();
    float qv[96];
    #pragma unroll
    for (int d=0;d<96;d++) qv[d] = b2f(Qc[(long)q*768 + h*96 + d]);
    for (int k=0;k<49;k++){
        float a = 0.f;
        #pragma unroll
        for (int d=0;d<96;d++) a += qv[d]*b2f(KVs[k*96+d]);
        Sm[q*49+k] = a*0.10206207f;
    }
    __syncthreads();
    for (int i=q; i<49*96; i+=256){ int k=i/96, d=i-k*96; KVs[i] = KV[(long)(b*49+k)*1536 + 768 + h*96 + d]; }
    float mx = -1e30f;
    for (int k=0;k<49;k++) mx = fmaxf(mx, Sm[q*49+k]);
    float sum = 0.f;
    for (int k=0;k<49;k++){ float e = __expf(Sm[q*49+k]-mx); Sm[q*49+k]=e; sum+=e; }
    float inv = 1.f/sum;
    __syncthreads();
    for (int d=0;d<96;d++){
        float a = 0.f;
        for (int k=0;k<49;k++) a += Sm[q*49+k]*b2f(KVs[k*96+d]);
        attn_out[(long)(b*256+q)*768 + h*96 + d] = f2b(a*inv);
    }
}

// ---------------- LayerNorm (wave per row), fp32 res/out, bf16 shadow, optional fused router ----------------
template<int MODE, bool ROUTE>
__global__ __launch_bounds__(256) void ln_k(
    const float* __restrict__ res, int resmod,
    const u16* __restrict__ add,
    const u16* __restrict__ OutE, const int* __restrict__ sot, const float2* __restrict__ w01,
    const float* __restrict__ g, const float* __restrict__ bb,
    const float* __restrict__ rw, const float* __restrict__ rb,
    int2* __restrict__ e01o, float2* __restrict__ w01o,
    float* __restrict__ out, u16* __restrict__ outb, int T)
{
    int wid = threadIdx.x >> 6, lane = threadIdx.x & 63;
    int t = blockIdx.x*4 + wid; if (t >= T) return;
    const float* rp = res + (long)(t % resmod)*768;
    float x[12];
    #pragma unroll
    for (int j=0;j<3;j++){
        float4 v = *(const float4*)(rp + j*256 + lane*4);
        x[j*4+0]=v.x; x[j*4+1]=v.y; x[j*4+2]=v.z; x[j*4+3]=v.w;
    }
    if (MODE == 0){
        const u16* ap = add + (long)t*768;
        #pragma unroll
        for (int j=0;j<3;j++){
            ushort4 v = *(const ushort4*)(ap + j*256 + lane*4);
            x[j*4+0]+=b2f(v.x); x[j*4+1]+=b2f(v.y); x[j*4+2]+=b2f(v.z); x[j*4+3]+=b2f(v.w);
        }
    } else {
        int s0 = sot[2*t], s1 = sot[2*t+1];
        float2 w = w01[t];
        const u16* p0 = OutE + (long)s0*768;
        const u16* p1 = OutE + (long)s1*768;
        #pragma unroll
        for (int j=0;j<3;j++){
            ushort4 v0 = *(const ushort4*)(p0 + j*256 + lane*4);
            ushort4 v1 = *(const ushort4*)(p1 + j*256 + lane*4);
            x[j*4+0] += w.x*b2f(v0.x) + w.y*b2f(v1.x);
            x[j*4+1] += w.x*b2f(v0.y) + w.y*b2f(v1.y);
            x[j*4+2] += w.x*b2f(v0.z) + w.y*b2f(v1.z);
            x[j*4+3] += w.x*b2f(v0.w) + w.y*b2f(v1.w);
        }
    }
    float s = 0.f;
    #pragma unroll
    for (int i=0;i<12;i++) s += x[i];
    #pragma unroll
    for (int off=32; off>=1; off>>=1) s += __shfl_xor(s, off, 64);
    float m = s*(1.f/768.f);
    float s2 = 0.f;
    #pragma unroll
    for (int i=0;i<12;i++){ float d = x[i]-m; s2 += d*d; }
    #pragma unroll
    for (int off=32; off>=1; off>>=1) s2 += __shfl_xor(s2, off, 64);
    float rstd = rsqrtf(s2*(1.f/768.f) + 1e-5f);
    float y[12];
    #pragma unroll
    for (int j=0;j<3;j++){
        int col = j*256 + lane*4;
        float4 gg = *(const float4*)(g + col);
        float4 bv = *(const float4*)(bb + col);
        y[j*4+0] = (x[j*4+0]-m)*rstd*gg.x + bv.x;
        y[j*4+1] = (x[j*4+1]-m)*rstd*gg.y + bv.y;
        y[j*4+2] = (x[j*4+2]-m)*rstd*gg.z + bv.z;
        y[j*4+3] = (x[j*4+3]-m)*rstd*gg.w + bv.w;
        float4 o; o.x=y[j*4+0]; o.y=y[j*4+1]; o.z=y[j*4+2]; o.w=y[j*4+3];
        *(float4*)(out + (long)t*768 + col) = o;
        if (outb != nullptr){
            ushort4 ob;
            ob.x = f2b(o.x); ob.y = f2b(o.y); ob.z = f2b(o.z); ob.w = f2b(o.w);
            *(ushort4*)(outb + (long)t*768 + col) = ob;
        }
    }
    if (ROUTE){
        float part[8];
        #pragma unroll
        for (int e=0;e<8;e++){
            const float* wp = rw + e*768;
            float a = 0.f;
            #pragma unroll
            for (int j=0;j<3;j++){
                float4 w4 = *(const float4*)(wp + j*256 + lane*4);
                a += y[j*4+0]*w4.x + y[j*4+1]*w4.y + y[j*4+2]*w4.z + y[j*4+3]*w4.w;
            }
            part[e] = a;
        }
        #pragma unroll
        for (int e=0;e<8;e++){
            #pragma unroll
            for (int off=32; off>=1; off>>=1) part[e] += __shfl_xor(part[e], off, 64);
        }
        if (lane == 0){
            float pe[8];
            float mx = -1e30f;
            #pragma unroll
            for (int e=0;e<8;e++){ pe[e] = part[e] + rb[e]; mx = fmaxf(mx, pe[e]); }
            float sum = 0.f;
            #pragma unroll
            for (int e=0;e<8;e++){ pe[e] = __expf(pe[e]-mx); sum += pe[e]; }
            float inv = 1.f/sum;
            #pragma unroll
            for (int e=0;e<8;e++) pe[e] *= inv;
            int i0 = 0;
            #pragma unroll
            for (int e=1;e<8;e++) if (pe[e] > pe[i0]) i0 = e;
            int i1 = -1;
            for (int e=0;e<8;e++){ if (e == i0) continue; if (i1 < 0 || pe[e] > pe[i1]) i1 = e; }
            float ex = __expf(pe[i1] - pe[i0]);
            float w0 = 1.f/(1.f+ex), w1 = ex/(1.f+ex);
            e01o[t] = int2{i0, i1};
            w01o[t] = float2{w0, w1};
        }
    }
}

// ---------------- deterministic slot assignment: ONE block of 1024, no global atomics ----------------
__global__ __launch_bounds__(1024) void route_build(const int2* __restrict__ e01,
                                                    int* __restrict__ aoff_g,
                                                    int* __restrict__ tos, int* __restrict__ sot,
                                                    u16* __restrict__ zbuf)
{
    __shared__ int wsum[8][16];
    __shared__ int wbase[8][16];
    __shared__ int aoff_s[9];
    int tid = threadIdx.x, lane = tid & 63, wid = tid >> 6;
    for (int s = tid; s < MOE_CAP; s += 1024) tos[s] = -1;   // pad slots default
    if (tid < 128) zbuf[tid] = 0;                            // zero page for gll redirects
    int t0 = tid * 8;
    int lc[8];
    #pragma unroll
    for (int e=0;e<8;e++) lc[e] = 0;
    #pragma unroll
    for (int i=0;i<8;i++){
        int2 e = e01[t0+i];
        lc[e.x]++; lc[e.y]++;
    }
    int excl[8];
    #pragma unroll
    for (int e=0;e<8;e++){
        int sc = lc[e];
        #pragma unroll
        for (int off=1; off<64; off<<=1){
            int n = __shfl_up(sc, off, 64);
            if (lane >= off) sc += n;
        }
        excl[e] = sc - lc[e];
        if (lane == 63) wsum[e][wid] = sc;
    }
    __syncthreads();
    if (tid == 0){
        int tot = 0;
        #pragma unroll
        for (int e=0;e<8;e++){
            int s = 0;
            #pragma unroll
            for (int w=0;w<16;w++){ wbase[e][w] = s; s += wsum[e][w]; }
            aoff_s[e] = tot;
            tot += (s + 127) & ~127;
        }
        aoff_s[8] = tot;
        #pragma unroll
        for (int e=0;e<9;e++) aoff_g[e] = aoff_s[e];
    }
    __syncthreads();
    int cur[8];
    #pragma unroll
    for (int e=0;e<8;e++) cur[e] = aoff_s[e] + wbase[e][wid] + excl[e];
    #pragma unroll
    for (int i=0;i<8;i++){
        int t = t0 + i;
        int2 e = e01[t];
        int s0 = cur[e.x]++;
        tos[s0] = t; sot[2*t]   = s0;
        int s1 = cur[e.y]++;
        tos[s1] = t; sot[2*t+1] = s1;
    }
}

// ---------------- host launch ----------------
extern "C" void kernel_launch(void* const* d_in, const int* in_sizes, int n_in,
                              void* d_out, int out_size, void* d_ws, size_t ws_size,
                              hipStream_t stream)
{
    (void)in_sizes; (void)n_in; (void)out_size;
    const float* images   = (const float*)d_in[0];
    const int*   type_ids = (const int*)d_in[1];
    const float* noise    = (const float*)d_in[2];
    const float* conv_w   = (const float*)d_in[3];
    const float* conv_b   = (const float*)d_in[4];
    const float* pos_emb  = (const float*)d_in[5];
    const float* type_emb = (const float*)d_in[6];
    const float* latents  = (const float*)d_in[7];
    const float* ca_in_w  = (const float*)d_in[8];
    const float* ca_in_b  = (const float*)d_in[9];
    const float* ca_out_w = (const float*)d_in[10];
    const float* ca_out_b = (const float*)d_in[11];
    const float* ca_ln_g  = (const float*)d_in[12];
    const float* ca_ln_b  = (const float*)d_in[13];
    const float* sa_in_w  = (const float*)d_in[14];
    const float* sa_in_b  = (const float*)d_in[15];
    const float* sa_out_w = (const float*)d_in[16];
    const float* sa_out_b = (const float*)d_in[17];
    const float* ln1_g    = (const float*)d_in[18];
    const float* ln1_b    = (const float*)d_in[19];
    const float* router_w = (const float*)d_in[20];
    const float* router_b = (const float*)d_in[21];
    const float* e_w1     = (const float*)d_in[22];
    const float* e_b1     = (const float*)d_in[23];
    const float* e_w2     = (const float*)d_in[24];
    const float* e_b2     = (const float*)d_in[25];
    const float* ln2_g    = (const float*)d_in[26];
    const float* ln2_b    = (const float*)d_in[27];
    float* dout = (float*)d_out;
    float* lat  = dout;               // fp32 latent state lives in output 0 region

    char* p = (char*)d_ws;
    auto alloc = [&](size_t n)->char*{ char* r = p; p += (n + 255) & ~(size_t)255; return r; };
    int*    order  = (int*)   alloc(32*196*4);
    int2*   e01    = (int2*)  alloc((size_t)T_TOK*8);
    float2* w01    = (float2*)alloc((size_t)T_TOK*8);
    int*    aoff   = (int*)   alloc(64);
    int*    tos    = (int*)   alloc((size_t)MOE_CAP*4);
    int*    sot    = (int*)   alloc((size_t)T_TOK*2*4);
    u16*    zbuf   = (u16*)   alloc(256);
    size_t aux_used = (size_t)(p - (char*)d_ws);
    // tiers: wb = latb + common + ALL converted weights (353.5 MB); big = latb+common; small = common
    const size_t WB_BYTES = 92798976ull + 260702208ull;
    bool wb  = ws_size >= aux_used + WB_BYTES;
    bool big = wb || ws_size >= aux_used + 92798976ull;
    u16* ar = (u16*)alloc(wb ? WB_BYTES : (big ? 92798976ull : 71303168ull));
    u16* latb   = big ? ar : nullptr;
    u16* common = big ? ar + 6291456 : ar;
    u16* wbufA  = wb ? ar + 6291456 + 40108032 : nullptr;
    // prologue layout (within common)
    u16* Ap  = common;                // 1664*768
    u16* vis = common + 1277952;      // 1664*768
    u16* KV  = common + 2555904;      // 1664*1536
    u16* Qc  = common + 5111808;      // 256*768
    u16* caO = common + 5308416;      // 8192*768
    u16* caM = common + 11599872;     // 8192*768
    // attn layout (within common)
    u16* Qb  = common;                // 8192*768
    u16* Vt  = common + VOFF;         // 256 z * 96 d * 256 k
    u16* S   = common + 18874368;     // 256 z * 256 * 256
    u16* aO  = common;                // attn_out (over Qb, dead after scores)
    u16* mha = common + KOFF;         // over Kb
    // MoE layout (within common)
    u16* Hbuf = common;                               // big: 17408*1536 ; small: 8704*1536
    u16* OutE = common + (big ? 26738688 : 13369344);
    // converted-weight layout (within wbufA) — all layers
    u16* cwb      = wbufA;                   // conv_w        589,824
    u16* cainb    = wbufA + 589824;          // ca_in_w     1,769,472
    u16* caoutb   = wbufA + 2359296;         // ca_out_w      589,824
    u16* winbAll  = wbufA + 2949120;         // sa_in_w  6× 1,769,472
    u16* woutbAll = wbufA + 13565952;        // sa_out_w 6×   589,824
    u16* w1bAll   = wbufA + 17104896;        // e_w1     6× 9,437,184
    u16* w2bAll   = wbufA + 73728000;        // e_w2     6× 9,437,184

    const float ONE = 1.0f;
    const long Z0 = 0;

    // ---- indices + weight pre-conversion + visible-only patch embed ----
    argsort_k<<<32, 256, 0, stream>>>(noise, order, dout, zbuf);
    patch_gather<<<312, 256, 0, stream>>>(images, order, Ap);
    if (wb){
        wconv<<<288, 256, 0, stream>>>(conv_w, cwb, 589824);
        wconv<<<864, 256, 0, stream>>>(ca_in_w, cainb, 1769472);
        wconv<<<288, 256, 0, stream>>>(ca_out_w, caoutb, 589824);
        wconv<<<5184, 256, 0, stream>>>(sa_in_w, winbAll, 10616832);
        wconv<<<1728, 256, 0, stream>>>(sa_out_w, woutbAll, 3538944);
        wconv<<<27648, 256, 0, stream>>>(e_w1, w1bAll, 56623104);
        wconv<<<27648, 256, 0, stream>>>(e_w2, w2bAll, 56623104);
        gemm_nt<64,64,true,false,0,false,false,true,true,false><<<dim3(6,26,1),256,0,stream>>>(Ap, cwb, conv_b, vis,
            1664,768,768, 768,768,768, ONE, 1, 768, Z0,Z0,Z0,Z0,Z0,Z0, nullptr,nullptr,zbuf,0, Z0,Z0);
        add_pos_type<<<588, 256, 0, stream>>>(vis, order, type_ids, pos_emb, type_emb);
        gemm_nt<64,128,true,false,0,true,false,true,false,false><<<dim3(6,2,1),256,0,stream>>>(latents, cainb, ca_in_b, Qc,
            256,768,768, 768,768,768, ONE, 1, 768, Z0,Z0,Z0,Z0,Z0,Z0, nullptr,nullptr,zbuf,0, Z0,Z0);
        gemm_nt<64,64,true,false,0,false,false,true,true,false><<<dim3(12,26,1),256,0,stream>>>(vis, cainb + 589824, ca_in_b + 768, KV,
            1664,1536,768, 768,768,1536, ONE, 1, 1536, Z0,Z0,Z0,Z0,Z0,Z0, nullptr,nullptr,zbuf,0, Z0,Z0);
        ca_attn<<<dim3(32,8), 256, 0, stream>>>(Qc, KV, caO);
        gemm_nt<64,64,true,false,0,false,false,true,true,false><<<dim3(6,128,1),256,0,stream>>>(caO, caoutb, ca_out_b, caM,
            T_TOK,768,768, 768,768,768, ONE, 1, 768, Z0,Z0,Z0,Z0,Z0,Z0, nullptr,nullptr,zbuf,0, Z0,Z0);
    } else {
        gemm_nt<64,128,true,false,0,false,true,false,false,false><<<dim3(6,13,1),256,0,stream>>>(Ap, conv_w, conv_b, vis,
            1664,768,768, 768,768,768, ONE, 1, 768, Z0,Z0,Z0,Z0,Z0,Z0, nullptr,nullptr,zbuf,0, Z0,Z0);
        add_pos_type<<<588, 256, 0, stream>>>(vis, order, type_ids, pos_emb, type_emb);
        gemm_nt<64,128,true,false,0,true,true,false,false,false><<<dim3(6,2,1),256,0,stream>>>(latents, ca_in_w, ca_in_b, Qc,
            256,768,768, 768,768,768, ONE, 1, 768, Z0,Z0,Z0,Z0,Z0,Z0, nullptr,nullptr,zbuf,0, Z0,Z0);
        gemm_nt<64,128,true,false,0,false,true,false,false,false><<<dim3(12,13,1),256,0,stream>>>(vis, ca_in_w + 768*768, ca_in_b + 768, KV,
            1664,1536,768, 768,768,1536, ONE, 1, 1536, Z0,Z0,Z0,Z0,Z0,Z0, nullptr,nullptr,zbuf,0, Z0,Z0);
        ca_attn<<<dim3(32,8), 256, 0, stream>>>(Qc, KV, caO);
        gemm_nt<64,128,true,false,0,false,true,false,false,false><<<dim3(6,64,1),256,0,stream>>>(caO, ca_out_w, ca_out_b, caM,
            T_TOK,768,768, 768,768,768, ONE, 1, 768, Z0,Z0,Z0,Z0,Z0,Z0, nullptr,nullptr,zbuf,0, Z0,Z0);
    }
    ln_k<0,false><<<2048, 256, 0, stream>>>(latents, 256, caM, nullptr,nullptr,nullptr, ca_ln_g, ca_ln_b,
        nullptr,nullptr,nullptr,nullptr, lat, latb, T_TOK);

    // ---- layers ----
    for (int l=0; l<6; l++){
        const float* b_in  = sa_in_b  + l*2304;
        const float* b_out = sa_out_b + l*768;
        const float* b1 = e_b1 + l*8*1536;
        const float* b2 = e_b2 + l*8*768;
        const float* rwl = router_w + l*8*768;
        const float* rbl = router_b + l*8;
        if (wb){
            const u16* winb  = winbAll  + (long)l*1769472;
            const u16* woutb = woutbAll + (long)l*589824;
            const u16* w1b   = w1bAll   + (long)l*9437184;
            const u16* w2b   = w2bAll   + (long)l*9437184;
            // fused QKV (PIPE): Q->Qb, K->Qb+KOFF, V->Vt (head-transposed, ushort4-fused stores)
            gemm_nt<64,128,true,false,3,false,false,true,true,true><<<dim3(18,64,1),256,0,stream>>>(latb, winb, b_in, Qb,
                T_TOK,2304,768, 768,768,0, ONE, 1, 2304, Z0,Z0,Z0,Z0,Z0,Z0, nullptr,nullptr,zbuf,0, KOFF, VOFF);
            scores_sm<<<dim3(4,256), 256, 0, stream>>>(Qb, Qb + KOFF, S);
            // PV: attn_out[b*256+q][h*96+d]
            gemm_nt<64,64,false,false,0,false,false,false,true,false><<<dim3(1,4,256),256,0,stream>>>(S, Vt, nullptr, aO,
                256,96,256, 256,256,768, ONE, 8, 96, 524288,65536, 196608,24576, 196608,96, nullptr,nullptr,zbuf,0, Z0,Z0);
            gemm_nt<64,64,true,false,0,false,false,true,true,false><<<dim3(6,128,1),256,0,stream>>>(aO, woutb, b_out, mha,
                T_TOK,768,768, 768,768,768, ONE, 1, 768, Z0,Z0,Z0,Z0,Z0,Z0, nullptr,nullptr,zbuf,0, Z0,Z0);
            ln_k<0,true><<<2048, 256, 0, stream>>>(lat, T_TOK, mha, nullptr,nullptr,nullptr, ln1_g + l*768, ln1_b + l*768,
                rwl, rbl, e01, w01, lat, latb, T_TOK);
            route_build<<<1, 1024, 0, stream>>>(e01, aoff, tos, sot, zbuf);
            gemm_nt<64,128,true,true,1,false,false,true,true,true><<<dim3(12,136,1),256,0,stream>>>(latb, w1b, b1, Hbuf,
                MOE_CAP,1536,768, 768,768,1536, ONE, 1, 1536, Z0,Z0,Z0,Z0,Z0,Z0,
                aoff, tos, zbuf, 0, (long)1536*768, 1536);
            gemm_nt<64,128,true,false,2,false,false,true,true,true><<<dim3(6,136,1),256,0,stream>>>(Hbuf, w2b, b2, OutE,
                MOE_CAP,768,1536, 1536,1536,768, ONE, 1, 768, Z0,Z0,Z0,Z0,Z0,Z0,
                aoff, tos, zbuf, 0, (long)768*1536, 768);
            ln_k<1,false><<<2048, 256, 0, stream>>>(lat, T_TOK, nullptr, OutE, sot, w01, ln2_g + l*768, ln2_b + l*768,
                nullptr,nullptr,nullptr,nullptr, lat, latb, T_TOK);
        } else {
            const float* w_in  = sa_in_w  + (long)l*2304*768;
            const float* w_out = sa_out_w + (long)l*768*768;
            const float* w1 = e_w1 + (long)l*8*1536*768;
            const float* w2 = e_w2 + (long)l*8*768*1536;
            if (big){
                gemm_nt<64,128,true,false,3,false,true,false,false,false><<<dim3(18,64,1),256,0,stream>>>(latb, w_in, b_in, Qb,
                    T_TOK,2304,768, 768,768,0, ONE, 1, 2304, Z0,Z0,Z0,Z0,Z0,Z0, nullptr,nullptr,zbuf,0, KOFF, VOFF);
            } else {
                gemm_nt<64,128,true,false,3,true,true,false,false,false><<<dim3(18,64,1),256,0,stream>>>(lat, w_in, b_in, Qb,
                    T_TOK,2304,768, 768,768,0, ONE, 1, 2304, Z0,Z0,Z0,Z0,Z0,Z0, nullptr,nullptr,zbuf,0, KOFF, VOFF);
            }
            scores_sm<<<dim3(4,256), 256, 0, stream>>>(Qb, Qb + KOFF, S);
            gemm_nt<64,128,false,false,0,false,false,false,false,false><<<dim3(1,2,256),256,0,stream>>>(S, Vt, nullptr, aO,
                256,96,256, 256,256,768, ONE, 8, 96, 524288,65536, 196608,24576, 196608,96, nullptr,nullptr,zbuf,0, Z0,Z0);
            gemm_nt<64,128,true,false,0,false,true,false,false,false><<<dim3(6,64,1),256,0,stream>>>(aO, w_out, b_out, mha,
                T_TOK,768,768, 768,768,768, ONE, 1, 768, Z0,Z0,Z0,Z0,Z0,Z0, nullptr,nullptr,zbuf,0, Z0,Z0);
            ln_k<0,true><<<2048, 256, 0, stream>>>(lat, T_TOK, mha, nullptr,nullptr,nullptr, ln1_g + l*768, ln1_b + l*768,
                rwl, rbl, e01, w01, lat, latb, T_TOK);
            route_build<<<1, 1024, 0, stream>>>(e01, aoff, tos, sot, zbuf);
            if (big){
                gemm_nt<64,128,true,true,1,false,true,false,false,false><<<dim3(12,136,1),256,0,stream>>>(latb, w1, b1, Hbuf,
                    MOE_CAP,1536,768, 768,768,1536, ONE, 1, 1536, Z0,Z0,Z0,Z0,Z0,Z0,
                    aoff, tos, zbuf, 0, (long)1536*768, 1536);
                gemm_nt<64,128,true,false,2,false,true,false,false,false><<<dim3(6,136,1),256,0,stream>>>(Hbuf, w2, b2, OutE,
                    MOE_CAP,768,1536, 1536,1536,768, ONE, 1, 768, Z0,Z0,Z0,Z0,Z0,Z0,
                    aoff, tos, zbuf, 0, (long)768*1536, 768);
            } else {
                for (int rb2=0; rb2<MOE_CAP; rb2+=MOE_HALF){
                    gemm_nt<64,128,true,true,1,true,true,false,false,false><<<dim3(12,68,1),256,0,stream>>>(lat, w1, b1, Hbuf,
                        MOE_HALF,1536,768, 768,768,1536, ONE, 1, 1536, Z0,Z0,Z0,Z0,Z0,Z0,
                        aoff, tos, zbuf, rb2, (long)1536*768, 1536);
                    gemm_nt<64,128,true,false,2,false,true,false,false,false><<<dim3(6,68,1),256,0,stream>>>(Hbuf, w2, b2, OutE,
                        MOE_HALF,768,1536, 1536,1536,768, ONE, 1, 768, Z0,Z0,Z0,Z0,Z0,Z0,
                        aoff, tos, zbuf, rb2, (long)768*1536, 768);
                }
            }
            ln_k<1,false><<<2048, 256, 0, stream>>>(lat, T_TOK, nullptr, OutE, sot, w01, ln2_g + l*768, ln2_b + l*768,
                nullptr,nullptr,nullptr,nullptr, lat, latb, T_TOK);
        }
    }
}

// Round 15
// 2218.772 us; speedup vs baseline: 1.2517x; 1.2517x over previous
//
#include <hip/hip_runtime.h>

typedef unsigned short u16;
typedef unsigned int u32;
typedef __attribute__((ext_vector_type(8))) u16 u16x8;
typedef __attribute__((ext_vector_type(8))) __bf16 bf16x8;
typedef __attribute__((ext_vector_type(4))) float f32x4;

#define DEV static __device__ __forceinline__

DEV float b2f(u16 u){ unsigned int i = ((unsigned int)u)<<16; float f; __builtin_memcpy(&f,&i,4); return f; }
DEV u16 f2b(float f){ unsigned int x; __builtin_memcpy(&x,&f,4); x = x + 0x7fffu + ((x>>16)&1u); return (u16)(x>>16); }

// async global->LDS 16B: HW writes lane i's data at ldsbase + i*16 (wave-uniform base)
DEV void gll16(const u16* g, u16* l){
    __builtin_amdgcn_global_load_lds(
        (const __attribute__((address_space(1))) u32*)(const void*)g,
        (__attribute__((address_space(3))) u32*)(void*)l, 16, 0, 0);
}

// load 8 contiguous elements as bf16x8-bits; F32 converts fp32->bf16 (RTN)
template<bool F32>
DEV u16x8 ld8(const void* base, long off){
    if constexpr (F32){
        const float* p = (const float*)base + off;
        float4 a = *(const float4*)p;
        float4 b = *(const float4*)(p+4);
        u16x8 r;
        r[0]=f2b(a.x); r[1]=f2b(a.y); r[2]=f2b(a.z); r[3]=f2b(a.w);
        r[4]=f2b(b.x); r[5]=f2b(b.y); r[6]=f2b(b.z); r[7]=f2b(b.w);
        return r;
    } else {
        return *(const u16x8*)((const u16*)base + off);
    }
}
template<bool F32>
DEV const void* vadd(const void* p, long elems){
    if constexpr (F32) return (const void*)((const float*)p + elems);
    else               return (const void*)((const u16*)p + elems);
}

// B=32 D=768 H=8 L=6 E=8 NL=256 P=16 IMG=224 NT=10 G=14 NP=196 HD=96 TOPK=2
#define LAT_ELEMS 6291456   // 32*256*768
#define NVIS 49
#define NMASK 147
#define T_TOK 8192          // 32*256
#define MOE_CAP 17408       // 2*8192 + 8*128 pad
#define MOE_HALF 8704
#define KOFF 6291456L       // Kb offset within common (elems)
#define VOFF 12582912L      // Vt offset within common (elems)

// ---------------- fp32 -> bf16 weight conversion (RTN, identical to staging) ----------------
__global__ __launch_bounds__(256) void wconv(const float* __restrict__ src, u16* __restrict__ dst, long n)
{
    long i = ((long)blockIdx.x*256 + threadIdx.x)*8;
    if (i >= n) return;
    *(u16x8*)(dst + i) = ld8<true>(src, i);
}

// ---------------- argsort (stable, ascending), fp32 noise, fp32 index outputs ----------------
__global__ __launch_bounds__(256) void argsort_k(const float* __restrict__ noise,
                                                 int* __restrict__ order,
                                                 float* __restrict__ dout,
                                                 u16* __restrict__ zbuf)
{
    __shared__ float vals[196];
    __shared__ int ord[196];
    int b = blockIdx.x, tid = threadIdx.x;
    if (b == 0 && tid < 128) zbuf[tid] = 0;     // zero page for gll redirects
    if (tid < 196) vals[tid] = noise[b*196 + tid];
    __syncthreads();
    if (tid < 196){
        float vi = vals[tid]; int rank = 0;
        for (int j=0;j<196;j++){ float vj = vals[j]; rank += (vj < vi) || (vj == vi && j < tid); }
        ord[rank] = tid;
    }
    __syncthreads();
    if (tid < 196){
        int v = ord[tid];
        order[b*196 + tid] = v;
        if (tid < NVIS) dout[LAT_ELEMS + b*NVIS + tid] = (float)v;
        else            dout[LAT_ELEMS + 32*NVIS + b*NMASK + (tid - NVIS)] = (float)v;
    }
}

// ---------------- gather visible patch pixels (fp32 images) into bf16 Ap (1664x768) ----------------
__global__ __launch_bounds__(256) void patch_gather(const float* __restrict__ images,
                                                    const int* __restrict__ order,
                                                    u16* __restrict__ Ap)
{
    int i = blockIdx.x*256 + threadIdx.x;   // over 1664*48
    int t = i/48, kc = i - t*48;
    if (t >= 1664) return;
    if (t >= 1568){
        u16x8 z{};
        *(u16x8*)(Ap + (long)t*768 + kc*16)     = z;
        *(u16x8*)(Ap + (long)t*768 + kc*16 + 8) = z;
        return;
    }
    int b = t/49, vi = t - b*49;
    int p = order[b*196 + vi];
    int c = kc >> 4, py = kc & 15;
    int gy = p/14, gx = p - gy*14;
    const float* src = images + (((long)(b*3 + c)*224 + gy*16 + py)*224 + gx*16);
    u16x8 o0 = ld8<true>(src, 0);
    u16x8 o1 = ld8<true>(src, 8);
    *(u16x8*)(Ap + (long)t*768 + kc*16)     = o0;
    *(u16x8*)(Ap + (long)t*768 + kc*16 + 8) = o1;
}

// ---------------- add pos_emb + type_emb (fp32) to bf16 vis ----------------
__global__ __launch_bounds__(256) void add_pos_type(u16* __restrict__ vis,
                                                    const int* __restrict__ order,
                                                    const int* __restrict__ type_ids,
                                                    const float* __restrict__ pos,
                                                    const float* __restrict__ temb)
{
    int i = blockIdx.x*256 + threadIdx.x;   // 1568*96
    int t = i/96, dc = (i - t*96)*8;
    if (t >= 1568) return;
    int b = t/49, vi = t - b*49;
    int p = order[b*196 + vi], tb = type_ids[b];
    u16x8 a = *(u16x8*)(vis + (long)t*768 + dc);
    const float* pp = pos  + (long)p*768 + dc;
    const float* tt = temb + (long)tb*768 + dc;
    float4 p0 = *(const float4*)pp, p1 = *(const float4*)(pp+4);
    float4 t0 = *(const float4*)tt, t1 = *(const float4*)(tt+4);
    u16x8 o;
    o[0]=f2b(b2f(a[0])+p0.x+t0.x); o[1]=f2b(b2f(a[1])+p0.y+t0.y);
    o[2]=f2b(b2f(a[2])+p0.z+t0.z); o[3]=f2b(b2f(a[3])+p0.w+t0.w);
    o[4]=f2b(b2f(a[4])+p1.x+t1.x); o[5]=f2b(b2f(a[5])+p1.y+t1.y);
    o[6]=f2b(b2f(a[6])+p1.z+t1.z); o[7]=f2b(b2f(a[7])+p1.w+t1.w);
    *(u16x8*)(vis + (long)t*768 + dc) = o;
}

// ---------------- generic NT GEMM ----------------
// C[M,N](bf16) = epi(scale*A[M,K]@B[N,K]^T + bias)
// MT: row-tile (64/128). GRP=0 plain (z-batched); GRP=1 MoE-FFN1 (A rows via tos[], MT=128);
// GRP=2 MoE-FFN2 (C at row_base+row); GRP=3 fused QKV epilogue (MT=128, V-third ushort4-fused).
// SWZ: bijective XCD remap. GLL: global_load_lds w16 staging.
// PIPE: T4 counted-vmcnt dbuf — REFUTED r14 (2220->2777us): 64KB LDS halves occupancy (17.5%),
//   pipeline doesn't pay at 128^2 2-phase (m132 regime). Keep false; kept for documentation.
// NOTE: min-waves pinned at 4 — (256,5) caps VGPR below acc needs -> scratch spill (r9: 364MB WRITE).
template<int BK, int MT, bool BIAS, bool GELU, int GRP, bool AF32, bool BF32, bool SWZ, bool GLL, bool PIPE>
__global__ __launch_bounds__(256,4) void gemm_nt(
    const void* __restrict__ A, const void* __restrict__ B, const float* __restrict__ bias,
    u16* __restrict__ C,
    int M, int N, int K, int lda, int ldb, int ldc,
    float scale, int ZLO, int NB,
    long sAh, long sAl, long sBh, long sBl, long sCh, long sCl,
    const int* __restrict__ aoff, const int* __restrict__ tos, const u16* __restrict__ zbuf,
    int row_base, long sBE, long sBiasE)
{
    int bx = blockIdx.x, by = blockIdx.y;
    if (SWZ){
        int nx = gridDim.x, ny = gridDim.y;
        int nwg = nx*ny;
        int flat = by*nx + bx;
        int q = nwg >> 3, r = nwg & 7;
        int xcd = flat & 7, idx = flat >> 3;
        int wg = (xcd < r ? xcd*(q+1) : r*(q+1) + (xcd - r)*q) + idx;
        bx = wg % nx; by = wg / nx;
    }
    int z = blockIdx.z; int zh = z / ZLO, zl = z - zh*ZLO;
    const void* Ab = vadd<AF32>(A, zh*sAh + zl*sAl);
    const void* Bb = vadd<BF32>(B, zh*sBh + zl*sBl);
    u16* Cb = C + zh*sCh + zl*sCl;
    const float* biasb = bias;
    int row0 = by*MT, col0 = bx*128;
    int lim = 0;
    if (GRP == 1 || GRP == 2){
        lim = aoff[8];
        int g0 = row_base + row0;
        if (g0 >= lim) return;
        int e = 0;
        #pragma unroll
        for (int i=1;i<8;i++) if (g0 >= aoff[i]) e = i;
        Bb = vadd<BF32>(B, (long)e*sBE);
        if (BIAS) biasb = bias + (long)e*sBiasE;
    }
    constexpr int SP = GLL ? BK : BK + 8;
    constexpr int MR = MT/32;           // acc row-frags per wave
    __shared__ __align__(16) u16 As[MT*SP];
    __shared__ __align__(16) u16 Bs[128*SP];
    int tid = threadIdx.x;
    int lane = tid & 63, wv = tid >> 6;
    int wr = (wv>>1)*(MT/2), wc = (wv&1)*64;
    f32x4 acc[MR][4];
    #pragma unroll
    for (int m=0;m<MR;m++){
        #pragma unroll
        for (int n=0;n<4;n++) acc[m][n] = f32x4{0.f,0.f,0.f,0.f};
    }
    constexpr int RPC = BK/8;           // 16B chunks per row
    constexpr int RPI = 64/RPC;         // rows per wave-issue (GLL)
    constexpr int NJA = MT*RPC/256;     // A issues per wave (GLL)
    constexpr int NJB = 128*RPC/256;    // B issues per wave (GLL)
    constexpr int PER = 128*RPC/256;    // chunks per thread per matrix (old path, MT=128)
    int tA[4];
    if (GRP == 1){
        #pragma unroll
        for (int j=0;j<NJA;j++){
            int r = wv*(MT/4) + j*RPI + (lane/RPC);
            tA[j] = tos[row_base + row0 + r];
        }
    }
    for (int k0=0; k0<K; k0+=BK){
        if constexpr (GLL){
            int ch = lane % RPC;
            #pragma unroll
            for (int j=0;j<NJA;j++){
                int r  = wv*(MT/4) + j*RPI + (lane/RPC);
                const u16* sa;
                if (GRP == 1){
                    int t = tA[j];
                    sa = (t >= 0) ? (const u16*)Ab + (long)t*lda + k0 + ch*8 : zbuf + ch*8;
                } else {
                    sa = (const u16*)Ab + (long)(row0+r)*lda + k0 + ch*8;
                }
                gll16(sa, As + (wv*(MT/4) + j*RPI)*BK);
            }
            #pragma unroll
            for (int j=0;j<NJB;j++){
                int r = wv*32 + j*RPI + (lane/RPC);
                const u16* sb = (col0 + r < NB) ? (const u16*)Bb + (long)(col0+r)*ldb + k0 + ch*8
                                                : zbuf + ch*8;
                gll16(sb, Bs + (wv*32 + j*RPI)*BK);
            }
        } else if constexpr (MT == 128){
            #pragma unroll
            for (int j=0;j<PER;j++){
                int c = j*256 + tid;
                int r = c / RPC, cc = (c - r*RPC)*8;
                u16x8 va{}, vb{};
                if (GRP == 1){
                    int t = tA[j];
                    if (t >= 0) va = ld8<AF32>(Ab, (long)t*lda + k0 + cc);
                } else {
                    va = ld8<AF32>(Ab, (long)(row0+r)*lda + k0 + cc);
                }
                if (col0 + r < NB) vb = ld8<BF32>(Bb, (long)(col0+r)*ldb + k0 + cc);
                *(u16x8*)(As + r*SP + cc) = va;
                *(u16x8*)(Bs + r*SP + cc) = vb;
            }
        }
        __syncthreads();
        #pragma unroll
        for (int kk=0; kk<BK/32; kk++){
            bf16x8 af[MR], bg[4];
            #pragma unroll
            for (int m=0;m<MR;m++)
                af[m] = *(const bf16x8*)(As + (wr + m*16 + (lane&15))*SP + kk*32 + (lane>>4)*8);
            #pragma unroll
            for (int n=0;n<4;n++)
                bg[n] = *(const bf16x8*)(Bs + (wc + n*16 + (lane&15))*SP + kk*32 + (lane>>4)*8);
            #pragma unroll
            for (int m=0;m<MR;m++){
                #pragma unroll
                for (int n=0;n<4;n++)
                    acc[m][n] = __builtin_amdgcn_mfma_f32_16x16x32_bf16(af[m], bg[n], acc[m][n], 0,0,0);
            }
        }
        __syncthreads();
    }
    if (GRP == 3){
        // fused QKV epilogue: M=8192 exact, all rows valid; V-third gets ushort4-fused stores
        #pragma unroll
        for (int m=0;m<MR;m++){
            int rbase = row0 + wr + m*16 + ((lane>>4)<<2);
            #pragma unroll
            for (int n=0;n<4;n++){
                int col = col0 + wc + n*16 + (lane&15);
                float bv = biasb[col];
                if (col < 1536){
                    u16* base = (col < 768) ? Cb : Cb + sBE - 768;
                    #pragma unroll
                    for (int j=0;j<4;j++)
                        base[(long)(rbase+j)*768 + col] = f2b(acc[m][n][j]*scale + bv);
                } else {
                    int c96 = col - 1536;
                    int h = c96/96, d = c96 - h*96;
                    ushort4 o4;
                    o4.x = f2b(acc[m][n][0]*scale + bv);
                    o4.y = f2b(acc[m][n][1]*scale + bv);
                    o4.z = f2b(acc[m][n][2]*scale + bv);
                    o4.w = f2b(acc[m][n][3]*scale + bv);
                    *(ushort4*)(Cb + sBiasE + ((long)((rbase>>8)*8 + h)*96 + d)*256 + (rbase & 255)) = o4;
                }
            }
        }
        return;
    }
    #pragma unroll
    for (int m=0;m<MR;m++){
        int rbase = row0 + wr + m*16 + ((lane>>4)<<2);
        #pragma unroll
        for (int n=0;n<4;n++){
            int col = col0 + wc + n*16 + (lane&15);
            if (col < N){
                float bv = BIAS ? biasb[col] : 0.f;
                #pragma unroll
                for (int j=0;j<4;j++){
                    int row = rbase + j;
                    bool ok = (row < M);
                    if (GRP == 1 || GRP == 2) ok = ok && (row_base + row) < lim;
                    if (ok){
                        float v = acc[m][n][j]*scale + bv;
                        if (GELU) v = 0.5f*v*(1.f + erff(v*0.70710678118f));
                        u16 ov = f2b(v);
                        if (GRP == 2){
                            Cb[(long)(row_base + row)*ldc + col] = ov;
                        } else {
                            Cb[(long)row*ldc + col] = ov;
                        }
                    }
                }
            }
        }
    }
}

// ---------------- fused scores+softmax: S[z] = softmax(Q K^T / sqrt(96)), bf16 out ----------------
// grid (4, 256): blockIdx.x = 64-row block, blockIdx.y = z = b*8+h. 4 waves; wave owns 16 rows x 256 cols.
__global__ __launch_bounds__(256,4) void scores_sm(const u16* __restrict__ Q,
                                                   const u16* __restrict__ K,
                                                   u16* __restrict__ S)
{
    __shared__ __align__(16) u16 As[64*32];
    __shared__ __align__(16) u16 Bs[256*32];
    int z = blockIdx.y;
    int b = z >> 3, h = z & 7;
    const u16* Ab = Q + (long)b*196608 + h*96 + (long)blockIdx.x*64*768;
    const u16* Bb = K + (long)b*196608 + h*96;
    int tid = threadIdx.x, lane = tid & 63, wv = tid >> 6;
    f32x4 acc[16];
    #pragma unroll
    for (int n=0;n<16;n++) acc[n] = f32x4{0.f,0.f,0.f,0.f};
    int ch = lane & 3, rr = lane >> 2;
    for (int k0=0;k0<96;k0+=32){
        gll16(Ab + (long)(wv*16 + rr)*768 + k0 + ch*8, As + (wv*16)*32);
        #pragma unroll
        for (int jj=0;jj<4;jj++)
            gll16(Bb + (long)(wv*64 + jj*16 + rr)*768 + k0 + ch*8, Bs + (wv*64 + jj*16)*32);
        __syncthreads();
        bf16x8 af = *(const bf16x8*)(As + (wv*16 + (lane&15))*32 + (lane>>4)*8);
        #pragma unroll
        for (int n=0;n<16;n++){
            bf16x8 bg = *(const bf16x8*)(Bs + (n*16 + (lane&15))*32 + (lane>>4)*8);
            acc[n] = __builtin_amdgcn_mfma_f32_16x16x32_bf16(af, bg, acc[n], 0,0,0);
        }
        __syncthreads();
    }
    const float SCL = 0.10206207f;    // 1/sqrt(96)
    u16* Sz = S + (long)z*65536 + (long)blockIdx.x*64*256;
    #pragma unroll
    for (int j=0;j<4;j++){
        float mx = -1e30f;
        #pragma unroll
        for (int n=0;n<16;n++) mx = fmaxf(mx, acc[n][j]);
        #pragma unroll
        for (int off=8; off>=1; off>>=1) mx = fmaxf(mx, __shfl_xor(mx, off, 64));
        float ev[16]; float sum = 0.f;
        #pragma unroll
        for (int n=0;n<16;n++){ ev[n] = __expf((acc[n][j]-mx)*SCL); sum += ev[n]; }
        #pragma unroll
        for (int off=8; off>=1; off>>=1) sum += __shfl_xor(sum, off, 64);
        float inv = 1.f/sum;
        int row = wv*16 + ((lane>>4)<<2) + j;
        #pragma unroll
        for (int n=0;n<16;n++) Sz[(long)row*256 + n*16 + (lane&15)] = f2b(ev[n]*inv);
    }
}

// ---------------- cross-attention (kv len 49), bf16 in/out ----------------
__global__ __launch_bounds__(256) void ca_attn(const u16* __restrict__ Qc,   // 256x768
                                               const u16* __restrict__ KV,   // 1664x1536 (K|V)
                                               u16* __restrict__ attn_out)   // 8192x768
{
    __shared__ float Sm[256*49];
    __shared__ u16 KVs[49*96];
    int b = blockIdx.x, h = blockIdx.y, q = threadIdx.x;
    for (int i=q; i<49*96; i+=256){ int k=i/96, d=i-k*96; KVs[i] = KV[(long)(b*49+k)*1536 + h*96 + d]; }
    __syncthreads();
    float qv[96];
    #pragma unroll
    for (int d=0;d<96;d++) qv[d] = b2f(Qc[(long)q*768 + h*96 + d]);
    for (int k=0;k<49;k++){
        float a = 0.f;
        #pragma unroll
        for (int d=0;d<96;d++) a += qv[d]*b2f(KVs[k*96+d]);
        Sm[q*49+k] = a*0.10206207f;
    }
    __syncthreads();
    for (int i=q; i<49*96; i+=256){ int k=i/96, d=i-k*96; KVs[i] = KV[(long)(b*49+k)*1536 + 768 + h*96 + d]; }
    float mx = -1e30f;
    for (int k=0;k<49;k++) mx = fmaxf(mx, Sm[q*49+k]);
    float sum = 0.f;
    for (int k=0;k<49;k++){ float e = __expf(Sm[q*49+k]-mx); Sm[q*49+k]=e; sum+=e; }
    float inv = 1.f/sum;
    __syncthreads();
    for (int d=0;d<96;d++){
        float a = 0.f;
        for (int k=0;k<49;k++) a += Sm[q*49+k]*b2f(KVs[k*96+d]);
        attn_out[(long)(b*256+q)*768 + h*96 + d] = f2b(a*inv);
    }
}

// ---------------- LayerNorm (wave per row), fp32 res/out, bf16 shadow, optional fused router ----------------
template<int MODE, bool ROUTE>
__global__ __launch_bounds__(256) void ln_k(
    const float* __restrict__ res, int resmod,
    const u16* __restrict__ add,
    const u16* __restrict__ OutE, const int* __restrict__ sot, const float2* __restrict__ w01,
    const float* __restrict__ g, const float* __restrict__ bb,
    const float* __restrict__ rw, const float* __restrict__ rb,
    int2* __restrict__ e01o, float2* __restrict__ w01o,
    float* __restrict__ out, u16* __restrict__ outb, int T)
{
    int wid = threadIdx.x >> 6, lane = threadIdx.x & 63;
    int t = blockIdx.x*4 + wid; if (t >= T) return;
    const float* rp = res + (long)(t % resmod)*768;
    float x[12];
    #pragma unroll
    for (int j=0;j<3;j++){
        float4 v = *(const float4*)(rp + j*256 + lane*4);
        x[j*4+0]=v.x; x[j*4+1]=v.y; x[j*4+2]=v.z; x[j*4+3]=v.w;
    }
    if (MODE == 0){
        const u16* ap = add + (long)t*768;
        #pragma unroll
        for (int j=0;j<3;j++){
            ushort4 v = *(const ushort4*)(ap + j*256 + lane*4);
            x[j*4+0]+=b2f(v.x); x[j*4+1]+=b2f(v.y); x[j*4+2]+=b2f(v.z); x[j*4+3]+=b2f(v.w);
        }
    } else {
        int s0 = sot[2*t], s1 = sot[2*t+1];
        float2 w = w01[t];
        const u16* p0 = OutE + (long)s0*768;
        const u16* p1 = OutE + (long)s1*768;
        #pragma unroll
        for (int j=0;j<3;j++){
            ushort4 v0 = *(const ushort4*)(p0 + j*256 + lane*4);
            ushort4 v1 = *(const ushort4*)(p1 + j*256 + lane*4);
            x[j*4+0] += w.x*b2f(v0.x) + w.y*b2f(v1.x);
            x[j*4+1] += w.x*b2f(v0.y) + w.y*b2f(v1.y);
            x[j*4+2] += w.x*b2f(v0.z) + w.y*b2f(v1.z);
            x[j*4+3] += w.x*b2f(v0.w) + w.y*b2f(v1.w);
        }
    }
    float s = 0.f;
    #pragma unroll
    for (int i=0;i<12;i++) s += x[i];
    #pragma unroll
    for (int off=32; off>=1; off>>=1) s += __shfl_xor(s, off, 64);
    float m = s*(1.f/768.f);
    float s2 = 0.f;
    #pragma unroll
    for (int i=0;i<12;i++){ float d = x[i]-m; s2 += d*d; }
    #pragma unroll
    for (int off=32; off>=1; off>>=1) s2 += __shfl_xor(s2, off, 64);
    float rstd = rsqrtf(s2*(1.f/768.f) + 1e-5f);
    float y[12];
    #pragma unroll
    for (int j=0;j<3;j++){
        int col = j*256 + lane*4;
        float4 gg = *(const float4*)(g + col);
        float4 bv = *(const float4*)(bb + col);
        y[j*4+0] = (x[j*4+0]-m)*rstd*gg.x + bv.x;
        y[j*4+1] = (x[j*4+1]-m)*rstd*gg.y + bv.y;
        y[j*4+2] = (x[j*4+2]-m)*rstd*gg.z + bv.z;
        y[j*4+3] = (x[j*4+3]-m)*rstd*gg.w + bv.w;
        float4 o; o.x=y[j*4+0]; o.y=y[j*4+1]; o.z=y[j*4+2]; o.w=y[j*4+3];
        *(float4*)(out + (long)t*768 + col) = o;
        if (outb != nullptr){
            ushort4 ob;
            ob.x = f2b(o.x); ob.y = f2b(o.y); ob.z = f2b(o.z); ob.w = f2b(o.w);
            *(ushort4*)(outb + (long)t*768 + col) = ob;
        }
    }
    if (ROUTE){
        float part[8];
        #pragma unroll
        for (int e=0;e<8;e++){
            const float* wp = rw + e*768;
            float a = 0.f;
            #pragma unroll
            for (int j=0;j<3;j++){
                float4 w4 = *(const float4*)(wp + j*256 + lane*4);
                a += y[j*4+0]*w4.x + y[j*4+1]*w4.y + y[j*4+2]*w4.z + y[j*4+3]*w4.w;
            }
            part[e] = a;
        }
        #pragma unroll
        for (int e=0;e<8;e++){
            #pragma unroll
            for (int off=32; off>=1; off>>=1) part[e] += __shfl_xor(part[e], off, 64);
        }
        if (lane == 0){
            float pe[8];
            float mx = -1e30f;
            #pragma unroll
            for (int e=0;e<8;e++){ pe[e] = part[e] + rb[e]; mx = fmaxf(mx, pe[e]); }
            float sum = 0.f;
            #pragma unroll
            for (int e=0;e<8;e++){ pe[e] = __expf(pe[e]-mx); sum += pe[e]; }
            float inv = 1.f/sum;
            #pragma unroll
            for (int e=0;e<8;e++) pe[e] *= inv;
            int i0 = 0;
            #pragma unroll
            for (int e=1;e<8;e++) if (pe[e] > pe[i0]) i0 = e;
            int i1 = -1;
            for (int e=0;e<8;e++){ if (e == i0) continue; if (i1 < 0 || pe[e] > pe[i1]) i1 = e; }
            float ex = __expf(pe[i1] - pe[i0]);
            float w0 = 1.f/(1.f+ex), w1 = ex/(1.f+ex);
            e01o[t] = int2{i0, i1};
            w01o[t] = float2{w0, w1};
        }
    }
}

// ---------------- deterministic slot assignment: ONE block of 1024, no global atomics ----------------
__global__ __launch_bounds__(1024) void route_build(const int2* __restrict__ e01,
                                                    int* __restrict__ aoff_g,
                                                    int* __restrict__ tos, int* __restrict__ sot,
                                                    u16* __restrict__ zbuf)
{
    __shared__ int wsum[8][16];
    __shared__ int wbase[8][16];
    __shared__ int aoff_s[9];
    int tid = threadIdx.x, lane = tid & 63, wid = tid >> 6;
    for (int s = tid; s < MOE_CAP; s += 1024) tos[s] = -1;   // pad slots default
    if (tid < 128) zbuf[tid] = 0;                            // zero page for gll redirects
    int t0 = tid * 8;
    int lc[8];
    #pragma unroll
    for (int e=0;e<8;e++) lc[e] = 0;
    #pragma unroll
    for (int i=0;i<8;i++){
        int2 e = e01[t0+i];
        lc[e.x]++; lc[e.y]++;
    }
    int excl[8];
    #pragma unroll
    for (int e=0;e<8;e++){
        int sc = lc[e];
        #pragma unroll
        for (int off=1; off<64; off<<=1){
            int n = __shfl_up(sc, off, 64);
            if (lane >= off) sc += n;
        }
        excl[e] = sc - lc[e];
        if (lane == 63) wsum[e][wid] = sc;
    }
    __syncthreads();
    if (tid == 0){
        int tot = 0;
        #pragma unroll
        for (int e=0;e<8;e++){
            int s = 0;
            #pragma unroll
            for (int w=0;w<16;w++){ wbase[e][w] = s; s += wsum[e][w]; }
            aoff_s[e] = tot;
            tot += (s + 127) & ~127;
        }
        aoff_s[8] = tot;
        #pragma unroll
        for (int e=0;e<9;e++) aoff_g[e] = aoff_s[e];
    }
    __syncthreads();
    int cur[8];
    #pragma unroll
    for (int e=0;e<8;e++) cur[e] = aoff_s[e] + wbase[e][wid] + excl[e];
    #pragma unroll
    for (int i=0;i<8;i++){
        int t = t0 + i;
        int2 e = e01[t];
        int s0 = cur[e.x]++;
        tos[s0] = t; sot[2*t]   = s0;
        int s1 = cur[e.y]++;
        tos[s1] = t; sot[2*t+1] = s1;
    }
}

// ---------------- host launch ----------------
extern "C" void kernel_launch(void* const* d_in, const int* in_sizes, int n_in,
                              void* d_out, int out_size, void* d_ws, size_t ws_size,
                              hipStream_t stream)
{
    (void)in_sizes; (void)n_in; (void)out_size;
    const float* images   = (const float*)d_in[0];
    const int*   type_ids = (const int*)d_in[1];
    const float* noise    = (const float*)d_in[2];
    const float* conv_w   = (const float*)d_in[3];
    const float* conv_b   = (const float*)d_in[4];
    const float* pos_emb  = (const float*)d_in[5];
    const float* type_emb = (const float*)d_in[6];
    const float* latents  = (const float*)d_in[7];
    const float* ca_in_w  = (const float*)d_in[8];
    const float* ca_in_b  = (const float*)d_in[9];
    const float* ca_out_w = (const float*)d_in[10];
    const float* ca_out_b = (const float*)d_in[11];
    const float* ca_ln_g  = (const float*)d_in[12];
    const float* ca_ln_b  = (const float*)d_in[13];
    const float* sa_in_w  = (const float*)d_in[14];
    const float* sa_in_b  = (const float*)d_in[15];
    const float* sa_out_w = (const float*)d_in[16];
    const float* sa_out_b = (const float*)d_in[17];
    const float* ln1_g    = (const float*)d_in[18];
    const float* ln1_b    = (const float*)d_in[19];
    const float* router_w = (const float*)d_in[20];
    const float* router_b = (const float*)d_in[21];
    const float* e_w1     = (const float*)d_in[22];
    const float* e_b1     = (const float*)d_in[23];
    const float* e_w2     = (const float*)d_in[24];
    const float* e_b2     = (const float*)d_in[25];
    const float* ln2_g    = (const float*)d_in[26];
    const float* ln2_b    = (const float*)d_in[27];
    float* dout = (float*)d_out;
    float* lat  = dout;               // fp32 latent state lives in output 0 region

    char* p = (char*)d_ws;
    auto alloc = [&](size_t n)->char*{ char* r = p; p += (n + 255) & ~(size_t)255; return r; };
    int*    order  = (int*)   alloc(32*196*4);
    int2*   e01    = (int2*)  alloc((size_t)T_TOK*8);
    float2* w01    = (float2*)alloc((size_t)T_TOK*8);
    int*    aoff   = (int*)   alloc(64);
    int*    tos    = (int*)   alloc((size_t)MOE_CAP*4);
    int*    sot    = (int*)   alloc((size_t)T_TOK*2*4);
    u16*    zbuf   = (u16*)   alloc(256);
    size_t aux_used = (size_t)(p - (char*)d_ws);
    // tiers: wb = latb + common + ALL converted weights (353.5 MB); big = latb+common; small = common
    const size_t WB_BYTES = 92798976ull + 260702208ull;
    bool wb  = ws_size >= aux_used + WB_BYTES;
    bool big = wb || ws_size >= aux_used + 92798976ull;
    u16* ar = (u16*)alloc(wb ? WB_BYTES : (big ? 92798976ull : 71303168ull));
    u16* latb   = big ? ar : nullptr;
    u16* common = big ? ar + 6291456 : ar;
    u16* wbufA  = wb ? ar + 6291456 + 40108032 : nullptr;
    // prologue layout (within common)
    u16* Ap  = common;                // 1664*768
    u16* vis = common + 1277952;      // 1664*768
    u16* KV  = common + 2555904;      // 1664*1536
    u16* Qc  = common + 5111808;      // 256*768
    u16* caO = common + 5308416;      // 8192*768
    u16* caM = common + 11599872;     // 8192*768
    // attn layout (within common)
    u16* Qb  = common;                // 8192*768
    u16* Vt  = common + VOFF;         // 256 z * 96 d * 256 k
    u16* S   = common + 18874368;     // 256 z * 256 * 256
    u16* aO  = common;                // attn_out (over Qb, dead after scores)
    u16* mha = common + KOFF;         // over Kb
    // MoE layout (within common)
    u16* Hbuf = common;                               // big: 17408*1536 ; small: 8704*1536
    u16* OutE = common + (big ? 26738688 : 13369344);
    // converted-weight layout (within wbufA) — all layers
    u16* cwb      = wbufA;                   // conv_w        589,824
    u16* cainb    = wbufA + 589824;          // ca_in_w     1,769,472
    u16* caoutb   = wbufA + 2359296;         // ca_out_w      589,824
    u16* winbAll  = wbufA + 2949120;         // sa_in_w  6× 1,769,472
    u16* woutbAll = wbufA + 13565952;        // sa_out_w 6×   589,824
    u16* w1bAll   = wbufA + 17104896;        // e_w1     6× 9,437,184
    u16* w2bAll   = wbufA + 73728000;        // e_w2     6× 9,437,184

    const float ONE = 1.0f;
    const long Z0 = 0;

    // ---- indices + weight pre-conversion + visible-only patch embed ----
    argsort_k<<<32, 256, 0, stream>>>(noise, order, dout, zbuf);
    patch_gather<<<312, 256, 0, stream>>>(images, order, Ap);
    if (wb){
        wconv<<<288, 256, 0, stream>>>(conv_w, cwb, 589824);
        wconv<<<864, 256, 0, stream>>>(ca_in_w, cainb, 1769472);
        wconv<<<288, 256, 0, stream>>>(ca_out_w, caoutb, 589824);
        wconv<<<5184, 256, 0, stream>>>(sa_in_w, winbAll, 10616832);
        wconv<<<1728, 256, 0, stream>>>(sa_out_w, woutbAll, 3538944);
        wconv<<<27648, 256, 0, stream>>>(e_w1, w1bAll, 56623104);
        wconv<<<27648, 256, 0, stream>>>(e_w2, w2bAll, 56623104);
        gemm_nt<64,64,true,false,0,false,false,true,true,false><<<dim3(6,26,1),256,0,stream>>>(Ap, cwb, conv_b, vis,
            1664,768,768, 768,768,768, ONE, 1, 768, Z0,Z0,Z0,Z0,Z0,Z0, nullptr,nullptr,zbuf,0, Z0,Z0);
        add_pos_type<<<588, 256, 0, stream>>>(vis, order, type_ids, pos_emb, type_emb);
        gemm_nt<64,128,true,false,0,true,false,true,false,false><<<dim3(6,2,1),256,0,stream>>>(latents, cainb, ca_in_b, Qc,
            256,768,768, 768,768,768, ONE, 1, 768, Z0,Z0,Z0,Z0,Z0,Z0, nullptr,nullptr,zbuf,0, Z0,Z0);
        gemm_nt<64,64,true,false,0,false,false,true,true,false><<<dim3(12,26,1),256,0,stream>>>(vis, cainb + 589824, ca_in_b + 768, KV,
            1664,1536,768, 768,768,1536, ONE, 1, 1536, Z0,Z0,Z0,Z0,Z0,Z0, nullptr,nullptr,zbuf,0, Z0,Z0);
        ca_attn<<<dim3(32,8), 256, 0, stream>>>(Qc, KV, caO);
        gemm_nt<64,64,true,false,0,false,false,true,true,false><<<dim3(6,128,1),256,0,stream>>>(caO, caoutb, ca_out_b, caM,
            T_TOK,768,768, 768,768,768, ONE, 1, 768, Z0,Z0,Z0,Z0,Z0,Z0, nullptr,nullptr,zbuf,0, Z0,Z0);
    } else {
        gemm_nt<64,128,true,false,0,false,true,false,false,false><<<dim3(6,13,1),256,0,stream>>>(Ap, conv_w, conv_b, vis,
            1664,768,768, 768,768,768, ONE, 1, 768, Z0,Z0,Z0,Z0,Z0,Z0, nullptr,nullptr,zbuf,0, Z0,Z0);
        add_pos_type<<<588, 256, 0, stream>>>(vis, order, type_ids, pos_emb, type_emb);
        gemm_nt<64,128,true,false,0,true,true,false,false,false><<<dim3(6,2,1),256,0,stream>>>(latents, ca_in_w, ca_in_b, Qc,
            256,768,768, 768,768,768, ONE, 1, 768, Z0,Z0,Z0,Z0,Z0,Z0, nullptr,nullptr,zbuf,0, Z0,Z0);
        gemm_nt<64,128,true,false,0,false,true,false,false,false><<<dim3(12,13,1),256,0,stream>>>(vis, ca_in_w + 768*768, ca_in_b + 768, KV,
            1664,1536,768, 768,768,1536, ONE, 1, 1536, Z0,Z0,Z0,Z0,Z0,Z0, nullptr,nullptr,zbuf,0, Z0,Z0);
        ca_attn<<<dim3(32,8), 256, 0, stream>>>(Qc, KV, caO);
        gemm_nt<64,128,true,false,0,false,true,false,false,false><<<dim3(6,64,1),256,0,stream>>>(caO, ca_out_w, ca_out_b, caM,
            T_TOK,768,768, 768,768,768, ONE, 1, 768, Z0,Z0,Z0,Z0,Z0,Z0, nullptr,nullptr,zbuf,0, Z0,Z0);
    }
    ln_k<0,false><<<2048, 256, 0, stream>>>(latents, 256, caM, nullptr,nullptr,nullptr, ca_ln_g, ca_ln_b,
        nullptr,nullptr,nullptr,nullptr, lat, latb, T_TOK);

    // ---- layers ----
    for (int l=0; l<6; l++){
        const float* b_in  = sa_in_b  + l*2304;
        const float* b_out = sa_out_b + l*768;
        const float* b1 = e_b1 + l*8*1536;
        const float* b2 = e_b2 + l*8*768;
        const float* rwl = router_w + l*8*768;
        const float* rbl = router_b + l*8;
        if (wb){
            const u16* winb  = winbAll  + (long)l*1769472;
            const u16* woutb = woutbAll + (long)l*589824;
            const u16* w1b   = w1bAll   + (long)l*9437184;
            const u16* w2b   = w2bAll   + (long)l*9437184;
            // fused QKV: Q->Qb, K->Qb+KOFF, V->Vt (head-transposed, ushort4-fused stores)
            gemm_nt<64,128,true,false,3,false,false,true,true,false><<<dim3(18,64,1),256,0,stream>>>(latb, winb, b_in, Qb,
                T_TOK,2304,768, 768,768,0, ONE, 1, 2304, Z0,Z0,Z0,Z0,Z0,Z0, nullptr,nullptr,zbuf,0, KOFF, VOFF);
            scores_sm<<<dim3(4,256), 256, 0, stream>>>(Qb, Qb + KOFF, S);
            // PV: attn_out[b*256+q][h*96+d]
            gemm_nt<64,64,false,false,0,false,false,false,true,false><<<dim3(1,4,256),256,0,stream>>>(S, Vt, nullptr, aO,
                256,96,256, 256,256,768, ONE, 8, 96, 524288,65536, 196608,24576, 196608,96, nullptr,nullptr,zbuf,0, Z0,Z0);
            gemm_nt<64,64,true,false,0,false,false,true,true,false><<<dim3(6,128,1),256,0,stream>>>(aO, woutb, b_out, mha,
                T_TOK,768,768, 768,768,768, ONE, 1, 768, Z0,Z0,Z0,Z0,Z0,Z0, nullptr,nullptr,zbuf,0, Z0,Z0);
            ln_k<0,true><<<2048, 256, 0, stream>>>(lat, T_TOK, mha, nullptr,nullptr,nullptr, ln1_g + l*768, ln1_b + l*768,
                rwl, rbl, e01, w01, lat, latb, T_TOK);
            route_build<<<1, 1024, 0, stream>>>(e01, aoff, tos, sot, zbuf);
            gemm_nt<64,128,true,true,1,false,false,true,true,false><<<dim3(12,136,1),256,0,stream>>>(latb, w1b, b1, Hbuf,
                MOE_CAP,1536,768, 768,768,1536, ONE, 1, 1536, Z0,Z0,Z0,Z0,Z0,Z0,
                aoff, tos, zbuf, 0, (long)1536*768, 1536);
            gemm_nt<64,128,true,false,2,false,false,true,true,false><<<dim3(6,136,1),256,0,stream>>>(Hbuf, w2b, b2, OutE,
                MOE_CAP,768,1536, 1536,1536,768, ONE, 1, 768, Z0,Z0,Z0,Z0,Z0,Z0,
                aoff, tos, zbuf, 0, (long)768*1536, 768);
            ln_k<1,false><<<2048, 256, 0, stream>>>(lat, T_TOK, nullptr, OutE, sot, w01, ln2_g + l*768, ln2_b + l*768,
                nullptr,nullptr,nullptr,nullptr, lat, latb, T_TOK);
        } else {
            const float* w_in  = sa_in_w  + (long)l*2304*768;
            const float* w_out = sa_out_w + (long)l*768*768;
            const float* w1 = e_w1 + (long)l*8*1536*768;
            const float* w2 = e_w2 + (long)l*8*768*1536;
            if (big){
                gemm_nt<64,128,true,false,3,false,true,false,false,false><<<dim3(18,64,1),256,0,stream>>>(latb, w_in, b_in, Qb,
                    T_TOK,2304,768, 768,768,0, ONE, 1, 2304, Z0,Z0,Z0,Z0,Z0,Z0, nullptr,nullptr,zbuf,0, KOFF, VOFF);
            } else {
                gemm_nt<64,128,true,false,3,true,true,false,false,false><<<dim3(18,64,1),256,0,stream>>>(lat, w_in, b_in, Qb,
                    T_TOK,2304,768, 768,768,0, ONE, 1, 2304, Z0,Z0,Z0,Z0,Z0,Z0, nullptr,nullptr,zbuf,0, KOFF, VOFF);
            }
            scores_sm<<<dim3(4,256), 256, 0, stream>>>(Qb, Qb + KOFF, S);
            gemm_nt<64,128,false,false,0,false,false,false,false,false><<<dim3(1,2,256),256,0,stream>>>(S, Vt, nullptr, aO,
                256,96,256, 256,256,768, ONE, 8, 96, 524288,65536, 196608,24576, 196608,96, nullptr,nullptr,zbuf,0, Z0,Z0);
            gemm_nt<64,128,true,false,0,false,true,false,false,false><<<dim3(6,64,1),256,0,stream>>>(aO, w_out, b_out, mha,
                T_TOK,768,768, 768,768,768, ONE, 1, 768, Z0,Z0,Z0,Z0,Z0,Z0, nullptr,nullptr,zbuf,0, Z0,Z0);
            ln_k<0,true><<<2048, 256, 0, stream>>>(lat, T_TOK, mha, nullptr,nullptr,nullptr, ln1_g + l*768, ln1_b + l*768,
                rwl, rbl, e01, w01, lat, latb, T_TOK);
            route_build<<<1, 1024, 0, stream>>>(e01, aoff, tos, sot, zbuf);
            if (big){
                gemm_nt<64,128,true,true,1,false,true,false,false,false><<<dim3(12,136,1),256,0,stream>>>(latb, w1, b1, Hbuf,
                    MOE_CAP,1536,768, 768,768,1536, ONE, 1, 1536, Z0,Z0,Z0,Z0,Z0,Z0,
                    aoff, tos, zbuf, 0, (long)1536*768, 1536);
                gemm_nt<64,128,true,false,2,false,true,false,false,false><<<dim3(6,136,1),256,0,stream>>>(Hbuf, w2, b2, OutE,
                    MOE_CAP,768,1536, 1536,1536,768, ONE, 1, 768, Z0,Z0,Z0,Z0,Z0,Z0,
                    aoff, tos, zbuf, 0, (long)768*1536, 768);
            } else {
                for (int rb2=0; rb2<MOE_CAP; rb2+=MOE_HALF){
                    gemm_nt<64,128,true,true,1,true,true,false,false,false><<<dim3(12,68,1),256,0,stream>>>(lat, w1, b1, Hbuf,
                        MOE_HALF,1536,768, 768,768,1536, ONE, 1, 1536, Z0,Z0,Z0,Z0,Z0,Z0,
                        aoff, tos, zbuf, rb2, (long)1536*768, 1536);
                    gemm_nt<64,128,true,false,2,false,true,false,false,false><<<dim3(6,68,1),256,0,stream>>>(Hbuf, w2, b2, OutE,
                        MOE_HALF,768,1536, 1536,1536,768, ONE, 1, 768, Z0,Z0,Z0,Z0,Z0,Z0,
                        aoff, tos, zbuf, rb2, (long)768*1536, 768);
                }
            }
            ln_k<1,false><<<2048, 256, 0, stream>>>(lat, T_TOK, nullptr, OutE, sot, w01, ln2_g + l*768, ln2_b + l*768,
                nullptr,nullptr,nullptr,nullptr, lat, latb, T_TOK);
        }
    }
}